// Round 3
// baseline (236.222 us; speedup 1.0000x reference)
//
#include <hip/hip_runtime.h>
#include <math.h>

// ---------------------------------------------------------------------------
// Encoder_Flows on MI355X — one fused kernel per layer.
// out = agg@w_l^T + b_l + x@w_r^T ; row-L2-normalize ; (relu on L4)
// agg affects only flattened rows [0,1024); agg@w_l^T == prefix_sum(x@w_l^T)/cnt.
// Per-layer grid = PBLKS proj blocks + 512 main blocks:
//   proj blocks: Y partial GEMM -> release(c1) -> join -> column scan -> release(c2)
//   main blocks: full GEMM; blocks with rows<1024 acquire(c2) AFTER their GEMM,
//   then add agg in the epilogue. proj+scan hides under the main GEMM.
// Co-residency: grid <= 576 <= 3 blocks/CU * 256 CUs (launch_bounds(256,3),
// LDS <= 40.5KB) -> spin-join is deadlock-free. Cross-XCD visibility via
// __threadfence (release) + __hip_atomic_load ACQUIRE/AGENT (acquire).
// ---------------------------------------------------------------------------

typedef __attribute__((ext_vector_type(8))) short short8;
typedef __attribute__((ext_vector_type(4))) float f32x4;

constexpr int NROWS = 32768;
constexpr int KROWS = 1024;

static __device__ __forceinline__ unsigned short f2bf(float f) {
    unsigned int u = __float_as_uint(f);
    return (unsigned short)((u + 0x7fffu + ((u >> 16) & 1u)) >> 16);
}

// ---- weight fp32->bf16 conversion + counter zeroing -----------------------
__global__ __launch_bounds__(256)
void cvt_weights(const float* __restrict__ wl1, const float* __restrict__ wr1,
                 const float* __restrict__ wl2, const float* __restrict__ wr2,
                 const float* __restrict__ wl3, const float* __restrict__ wr3,
                 const float* __restrict__ wl4, const float* __restrict__ wr4,
                 unsigned short* __restrict__ dst, unsigned int* __restrict__ cnt)
{
    if (blockIdx.x == 0 && threadIdx.x < 8) cnt[threadIdx.x] = 0u;
    int g = (blockIdx.x * 256 + threadIdx.x) * 4;
    const float* src; int off;
    if      (g < 131072) { src = wl1; off = g; }
    else if (g < 262144) { src = wr1; off = g - 131072; }
    else if (g < 294912) { src = wl2; off = g - 262144; }
    else if (g < 327680) { src = wr2; off = g - 294912; }
    else if (g < 360448) { src = wl3; off = g - 327680; }
    else if (g < 393216) { src = wr3; off = g - 360448; }
    else if (g < 425984) { src = wl4; off = g - 393216; }
    else                 { src = wr4; off = g - 425984; }
    float4 v = *reinterpret_cast<const float4*>(src + off);
    ushort4 o;
    o.x = f2bf(v.x); o.y = f2bf(v.y); o.z = f2bf(v.z); o.w = f2bf(v.w);
    *reinterpret_cast<ushort4*>(dst + g) = o;
}

// ---- register staging helpers (tile ROWS x 64, XOR-swizzled LDS) ----------
template<int ROWS>
struct RegsBF {
    short8 v[ROWS / 32];
    __device__ __forceinline__ void load(const unsigned short* src, int ld,
                                         int r0, int k0, int t) {
#pragma unroll
        for (int j = 0; j < ROWS / 32; ++j) {
            int idx = j * 256 + t; int r = idx >> 3, f = idx & 7;
            v[j] = *reinterpret_cast<const short8*>(
                src + (size_t)(r0 + r) * ld + k0 + f * 8);
        }
    }
    __device__ __forceinline__ void store(unsigned short* buf, int t) {
#pragma unroll
        for (int j = 0; j < ROWS / 32; ++j) {
            int idx = j * 256 + t; int r = idx >> 3, f = idx & 7;
            int off = (r * 128 + f * 16) ^ ((r & 7) << 4);
            *reinterpret_cast<short8*>((char*)buf + off) = v[j];
        }
    }
};

template<int ROWS>
struct RegsF32 {
    float4 v[ROWS / 16];
    __device__ __forceinline__ void load(const float* src, int ld,
                                         int r0, int k0, int t) {
#pragma unroll
        for (int j = 0; j < ROWS / 32; ++j) {
            int idx = j * 256 + t; int r = idx >> 3, f = idx & 7;
            const float* p = src + (size_t)(r0 + r) * ld + k0 + f * 8;
            v[2 * j]     = *reinterpret_cast<const float4*>(p);
            v[2 * j + 1] = *reinterpret_cast<const float4*>(p + 4);
        }
    }
    __device__ __forceinline__ void store(unsigned short* buf, int t) {
#pragma unroll
        for (int j = 0; j < ROWS / 32; ++j) {
            int idx = j * 256 + t; int r = idx >> 3, f = idx & 7;
            float4 a = v[2 * j], b = v[2 * j + 1];
            short8 s;
            s[0] = (short)f2bf(a.x); s[1] = (short)f2bf(a.y);
            s[2] = (short)f2bf(a.z); s[3] = (short)f2bf(a.w);
            s[4] = (short)f2bf(b.x); s[5] = (short)f2bf(b.y);
            s[6] = (short)f2bf(b.z); s[7] = (short)f2bf(b.w);
            int off = (r * 128 + f * 16) ^ ((r & 7) << 4);
            *reinterpret_cast<short8*>((char*)buf + off) = s;
        }
    }
};

// ---------------------------------------------------------------------------
// Fused layer kernel.  MODE 1: bf16 out.  MODE 2: fp32 out + relu + scalar.
// ---------------------------------------------------------------------------
template<int DOUT, int WM, int WN, int PBLKS, int KSPLIT, int MODE, bool AFP32>
__global__ __launch_bounds__(256, 3)
void layer_kernel(const void* __restrict__ Xv,
                  const unsigned short* __restrict__ Wl,
                  const unsigned short* __restrict__ Wr,
                  const float* __restrict__ bias,
                  float* __restrict__ Yp, float* __restrict__ aggp,
                  float* __restrict__ outf, unsigned short* __restrict__ outb,
                  unsigned int* __restrict__ c1, unsigned int* __restrict__ c2,
                  int din)
{
    constexpr int BM = 64, BN = WN * 64, FM = BM / (WM * 16);
    constexpr int CPB = DOUT / PBLKS;          // scan columns per proj block
    __shared__ unsigned short Abuf[BM * 64];
    __shared__ unsigned short Bbuf[BN * 64];
    __shared__ float ssred[WN * BM];
    __shared__ float wsum[4];

    const int t = threadIdx.x, wvid = t >> 6, lane = t & 63;
    const int wr_ = wvid / WN, wc = wvid % WN;
    const int bid = blockIdx.x;
    const bool isproj = bid < PBLKS;

    if (MODE == 2 && bid == PBLKS && t == 0)
        outf[(size_t)NROWS * 256] = 1.0f;      // tuple's python scalar 1

    int i0, kb, nt;
    const unsigned short* W;
    if (isproj) {
        int pslab = bid >> 4, pi = bid & 15;
        i0 = pi * 64;
        int kchunk = din / KSPLIT;
        kb = pslab * kchunk; nt = kchunk >> 6; W = Wl;
    } else {
        i0 = (bid - PBLKS) * 64; kb = 0; nt = din >> 6; W = Wr;
    }

    f32x4 acc[FM][4];
#pragma unroll
    for (int fi = 0; fi < FM; ++fi)
#pragma unroll
        for (int fj = 0; fj < 4; ++fj) acc[fi][fj] = (f32x4){0.f, 0.f, 0.f, 0.f};

    RegsBF<BN> brg;
    RegsF32<BM> arf;
    RegsBF<BM> arb;
    if (AFP32) arf.load((const float*)Xv, din, i0, kb, t);
    else       arb.load((const unsigned short*)Xv, din, i0, kb, t);
    brg.load(W, din, 0, kb, t);

    for (int kt = 0; kt < nt; ++kt) {
        if (kt) __syncthreads();               // consumers of prev tile done
        if (AFP32) arf.store(Abuf, t); else arb.store(Abuf, t);
        brg.store(Bbuf, t);
        __syncthreads();
        if (kt + 1 < nt) {                     // prefetch next tile into regs
            int kn = kb + (kt + 1) * 64;
            if (AFP32) arf.load((const float*)Xv, din, i0, kn, t);
            else       arb.load((const unsigned short*)Xv, din, i0, kn, t);
            brg.load(W, din, 0, kn, t);
        }
#pragma unroll
        for (int kk = 0; kk < 2; ++kk) {
            short8 a[FM], b[4];
#pragma unroll
            for (int fi = 0; fi < FM; ++fi) {
                int rA = wr_ * (BM / WM) + fi * 16 + (lane & 15);
                int off = (rA * 128 + kk * 64 + (lane >> 4) * 16) ^ ((rA & 7) << 4);
                a[fi] = *reinterpret_cast<const short8*>((const char*)Abuf + off);
            }
#pragma unroll
            for (int fj = 0; fj < 4; ++fj) {
                int rB = wc * 64 + fj * 16 + (lane & 15);
                int off = (rB * 128 + kk * 64 + (lane >> 4) * 16) ^ ((rB & 7) << 4);
                b[fj] = *reinterpret_cast<const short8*>((const char*)Bbuf + off);
            }
#pragma unroll
            for (int fi = 0; fi < FM; ++fi)
#pragma unroll
                for (int fj = 0; fj < 4; ++fj)
                    acc[fi][fj] = __builtin_amdgcn_mfma_f32_16x16x32_bf16(
                        a[fi], b[fj], acc[fi][fj], 0, 0, 0);
        }
    }

    // C/D frag layout: col = lane&15, row = (lane>>4)*4 + reg
    if (isproj) {
        float* dst = Yp + (size_t)(bid >> 4) * KROWS * DOUT;
#pragma unroll
        for (int fi = 0; fi < FM; ++fi)
#pragma unroll
            for (int fj = 0; fj < 4; ++fj)
#pragma unroll
                for (int reg = 0; reg < 4; ++reg) {
                    int rl = wr_ * (BM / WM) + fi * 16 + ((lane >> 4) << 2) + reg;
                    int cl = wc * 64 + fj * 16 + (lane & 15);
                    dst[(size_t)(i0 + rl) * DOUT + cl] = acc[fi][fj][reg];
                }
        __syncthreads();                       // drain stores (vmcnt0 at barrier)
        if (t == 0) {
            __threadfence();                   // release Y partials agent-wide
            atomicAdd(c1, 1u);
            while (__hip_atomic_load(c1, __ATOMIC_ACQUIRE,
                                     __HIP_MEMORY_SCOPE_AGENT) < (unsigned)PBLKS)
                __builtin_amdgcn_s_sleep(8);
        }
        __syncthreads();
        // ---- column scan: exclusive prefix-mean over 1024 rows ----
        for (int cc = 0; cc < CPB; ++cc) {
            int o = bid * CPB + cc;
            float v[4];
#pragma unroll
            for (int j = 0; j < 4; ++j) {
                int i = t * 4 + j;
                float s = 0.f;
#pragma unroll
                for (int sp = 0; sp < KSPLIT; ++sp)
                    s += Yp[(size_t)sp * KROWS * DOUT + (size_t)i * DOUT + o];
                v[j] = s;
            }
            float tot = v[0] + v[1] + v[2] + v[3];
            float x = tot;
#pragma unroll
            for (int d = 1; d < 64; d <<= 1) {
                float y = __shfl_up(x, d, 64);
                if (lane >= d) x += y;
            }
            if (lane == 63) wsum[wvid] = x;
            __syncthreads();
            float base = 0.f;
            for (int ww = 0; ww < wvid; ++ww) base += wsum[ww];
            float run = base + x - tot;
#pragma unroll
            for (int j = 0; j < 4; ++j) {
                int i = t * 4 + j;
                aggp[(size_t)i * DOUT + o] = run / fmaxf((float)i, 1.0f);
                run += v[j];
            }
            __syncthreads();
        }
        if (t == 0) { __threadfence(); atomicAdd(c2, 1u); }
        return;
    }

    // ---- main epilogue ----
    const bool hasagg = (i0 < KROWS);
    if (hasagg) {                              // GEMM done; scan is long since
        if (t == 0) {                          // finished -> near-zero wait
            while (__hip_atomic_load(c2, __ATOMIC_ACQUIRE,
                                     __HIP_MEMORY_SCOPE_AGENT) < (unsigned)PBLKS)
                __builtin_amdgcn_s_sleep(8);
        }
        __syncthreads();
    }

    float bb[4];
#pragma unroll
    for (int fj = 0; fj < 4; ++fj) bb[fj] = bias[wc * 64 + fj * 16 + (lane & 15)];

#pragma unroll
    for (int fi = 0; fi < FM; ++fi)
#pragma unroll
        for (int fj = 0; fj < 4; ++fj)
#pragma unroll
            for (int reg = 0; reg < 4; ++reg) {
                int rl = wr_ * (BM / WM) + fi * 16 + ((lane >> 4) << 2) + reg;
                int cl = wc * 64 + fj * 16 + (lane & 15);
                float v = acc[fi][fj][reg] + bb[fj];
                if (hasagg) v += aggp[(size_t)(i0 + rl) * DOUT + cl];
                acc[fi][fj][reg] = v;
            }

    float sstot[FM][4];
#pragma unroll
    for (int fi = 0; fi < FM; ++fi)
#pragma unroll
        for (int reg = 0; reg < 4; ++reg) {
            float s = 0.f;
#pragma unroll
            for (int fj = 0; fj < 4; ++fj) {
                float v = acc[fi][fj][reg];
                s += v * v;
            }
#pragma unroll
            for (int m = 8; m >= 1; m >>= 1) s += __shfl_xor(s, m);
            if ((lane & 15) == 0) {
                int rl = wr_ * (BM / WM) + fi * 16 + ((lane >> 4) << 2) + reg;
                ssred[wc * BM + rl] = s;
            }
        }
    __syncthreads();
#pragma unroll
    for (int fi = 0; fi < FM; ++fi)
#pragma unroll
        for (int reg = 0; reg < 4; ++reg) {
            int rl = wr_ * (BM / WM) + fi * 16 + ((lane >> 4) << 2) + reg;
            float s = 0.f;
#pragma unroll
            for (int c = 0; c < WN; ++c) s += ssred[c * BM + rl];
            sstot[fi][reg] = 1.0f / fmaxf(sqrtf(s), 1e-12f);
        }

#pragma unroll
    for (int fi = 0; fi < FM; ++fi)
#pragma unroll
        for (int fj = 0; fj < 4; ++fj)
#pragma unroll
            for (int reg = 0; reg < 4; ++reg) {
                int rl = wr_ * (BM / WM) + fi * 16 + ((lane >> 4) << 2) + reg;
                int cl = wc * 64 + fj * 16 + (lane & 15);
                float v = acc[fi][fj][reg] * sstot[fi][reg];
                if (MODE == 2) {
                    v = fmaxf(v, 0.f);
                    outf[(size_t)(i0 + rl) * DOUT + cl] = v;
                } else {
                    outb[(size_t)(i0 + rl) * DOUT + cl] = f2bf(v);
                }
            }
}

extern "C" void kernel_launch(void* const* d_in, const int* in_sizes, int n_in,
                              void* d_out, int out_size, void* d_ws, size_t ws_size,
                              hipStream_t stream)
{
    const float* flow = (const float*)d_in[0];
    const float* wl1 = (const float*)d_in[1];
    const float* bl1 = (const float*)d_in[2];
    const float* wr1 = (const float*)d_in[3];
    const float* wl2 = (const float*)d_in[4];
    const float* bl2 = (const float*)d_in[5];
    const float* wr2 = (const float*)d_in[6];
    const float* wl3 = (const float*)d_in[7];
    const float* bl3 = (const float*)d_in[8];
    const float* wr3 = (const float*)d_in[9];
    const float* wl4 = (const float*)d_in[10];
    const float* bl4 = (const float*)d_in[11];
    const float* wr4 = (const float*)d_in[12];
    float* out = (float*)d_out;

    char* p = (char*)d_ws;
    unsigned short* wbf = (unsigned short*)p;          p += 1 << 20;
    unsigned short* xA  = (unsigned short*)p;          p += (size_t)NROWS * 128 * 2;
    unsigned short* xB  = (unsigned short*)p;          p += (size_t)NROWS * 256 * 2;
    float* Yp   = (float*)p;                           p += (size_t)4 * KROWS * 256 * 4;
    float* aggp = (float*)p;                           p += (size_t)KROWS * 256 * 4;
    unsigned int* cnt = (unsigned int*)p;

    const unsigned short* wl1b = wbf;
    const unsigned short* wr1b = wbf + 131072;
    const unsigned short* wl2b = wbf + 262144;
    const unsigned short* wr2b = wbf + 294912;
    const unsigned short* wl3b = wbf + 327680;
    const unsigned short* wr3b = wbf + 360448;
    const unsigned short* wl4b = wbf + 393216;
    const unsigned short* wr4b = wbf + 425984;

    cvt_weights<<<448, 256, 0, stream>>>(wl1, wr1, wl2, wr2, wl3, wr3, wl4, wr4,
                                         wbf, cnt);

    // L1: din=1024, dout=128, X = flow (fp32), PBLKS=64 (ksplit 4)
    layer_kernel<128, 2, 2, 64, 4, 1, true><<<576, 256, 0, stream>>>(
        flow, wl1b, wr1b, bl1, Yp, aggp, nullptr, xA, cnt + 0, cnt + 1, 1024);

    // L2: din=128, dout=256, PBLKS=32 (ksplit 2)
    layer_kernel<256, 1, 4, 32, 2, 1, false><<<544, 256, 0, stream>>>(
        xA, wl2b, wr2b, bl2, Yp, aggp, nullptr, xB, cnt + 2, cnt + 3, 128);

    // L3: din=256, dout=128
    layer_kernel<128, 2, 2, 32, 2, 1, false><<<544, 256, 0, stream>>>(
        xB, wl3b, wr3b, bl3, Yp, aggp, nullptr, xA, cnt + 4, cnt + 5, 256);

    // L4: din=128, dout=256, relu -> fp32 out (+ tuple scalar)
    layer_kernel<256, 1, 4, 32, 2, 2, false><<<544, 256, 0, stream>>>(
        xA, wl4b, wr4b, bl4, Yp, aggp, out, nullptr, cnt + 6, cnt + 7, 128);
}

// Round 4
// 133.728 us; speedup vs baseline: 1.7664x; 1.7664x over previous
//
#include <hip/hip_runtime.h>
#include <math.h>

// ---------------------------------------------------------------------------
// Encoder_Flows on MI355X — separate kernels (no inter-block spins).
// Per layer: proj GEMM (Y = x[:1024] @ w_l^T, split-K) -> column scan
// (exclusive prefix-mean) -> main GEMM (bias + agg + L2-normalize, +relu L4).
// All GEMMs bf16 MFMA 16x16x32, fp32 accumulate. BM=32 mains -> 1024 blocks
// (4 blocks/CU) for latency hiding; XOR-swizzled LDS (T2) for conflict-free
// ds_read_b128.
// ---------------------------------------------------------------------------

typedef __attribute__((ext_vector_type(8))) short short8;
typedef __attribute__((ext_vector_type(4))) float f32x4;

constexpr int NROWS = 32768;
constexpr int KROWS = 1024;

static __device__ __forceinline__ unsigned short f2bf(float f) {
    unsigned int u = __float_as_uint(f);
    return (unsigned short)((u + 0x7fffu + ((u >> 16) & 1u)) >> 16);
}

// ---- weight fp32->bf16 conversion (+ tuple scalar write) ------------------
__global__ __launch_bounds__(256)
void cvt_weights(const float* __restrict__ wl1, const float* __restrict__ wr1,
                 const float* __restrict__ wl2, const float* __restrict__ wr2,
                 const float* __restrict__ wl3, const float* __restrict__ wr3,
                 const float* __restrict__ wl4, const float* __restrict__ wr4,
                 unsigned short* __restrict__ dst, float* __restrict__ outscalar)
{
    if (blockIdx.x == 0 && threadIdx.x == 0) outscalar[0] = 1.0f;
    int g = (blockIdx.x * 256 + threadIdx.x) * 4;
    const float* src; int off;
    if      (g < 131072) { src = wl1; off = g; }
    else if (g < 262144) { src = wr1; off = g - 131072; }
    else if (g < 294912) { src = wl2; off = g - 262144; }
    else if (g < 327680) { src = wr2; off = g - 294912; }
    else if (g < 360448) { src = wl3; off = g - 327680; }
    else if (g < 393216) { src = wr3; off = g - 360448; }
    else if (g < 425984) { src = wl4; off = g - 393216; }
    else                 { src = wr4; off = g - 425984; }
    float4 v = *reinterpret_cast<const float4*>(src + off);
    ushort4 o;
    o.x = f2bf(v.x); o.y = f2bf(v.y); o.z = f2bf(v.z); o.w = f2bf(v.w);
    *reinterpret_cast<ushort4*>(dst + g) = o;
}

// ---- register staging helpers (tile ROWS x 64, XOR-swizzled LDS) ----------
template<int ROWS>
struct RegsBF {
    short8 v[ROWS / 32];
    __device__ __forceinline__ void load(const unsigned short* src, int ld,
                                         int r0, int k0, int t) {
#pragma unroll
        for (int j = 0; j < ROWS / 32; ++j) {
            int idx = j * 256 + t; int r = idx >> 3, f = idx & 7;
            v[j] = *reinterpret_cast<const short8*>(
                src + (size_t)(r0 + r) * ld + k0 + f * 8);
        }
    }
    __device__ __forceinline__ void store(unsigned short* buf, int t) {
#pragma unroll
        for (int j = 0; j < ROWS / 32; ++j) {
            int idx = j * 256 + t; int r = idx >> 3, f = idx & 7;
            int off = (r * 128 + f * 16) ^ ((r & 7) << 4);
            *reinterpret_cast<short8*>((char*)buf + off) = v[j];
        }
    }
};

template<int ROWS>
struct RegsF32 {
    float4 v[ROWS / 16];
    __device__ __forceinline__ void load(const float* src, int ld,
                                         int r0, int k0, int t) {
#pragma unroll
        for (int j = 0; j < ROWS / 32; ++j) {
            int idx = j * 256 + t; int r = idx >> 3, f = idx & 7;
            const float* p = src + (size_t)(r0 + r) * ld + k0 + f * 8;
            v[2 * j]     = *reinterpret_cast<const float4*>(p);
            v[2 * j + 1] = *reinterpret_cast<const float4*>(p + 4);
        }
    }
    __device__ __forceinline__ void store(unsigned short* buf, int t) {
#pragma unroll
        for (int j = 0; j < ROWS / 32; ++j) {
            int idx = j * 256 + t; int r = idx >> 3, f = idx & 7;
            float4 a = v[2 * j], b = v[2 * j + 1];
            short8 s;
            s[0] = (short)f2bf(a.x); s[1] = (short)f2bf(a.y);
            s[2] = (short)f2bf(a.z); s[3] = (short)f2bf(a.w);
            s[4] = (short)f2bf(b.x); s[5] = (short)f2bf(b.y);
            s[6] = (short)f2bf(b.z); s[7] = (short)f2bf(b.w);
            int off = (r * 128 + f * 16) ^ ((r & 7) << 4);
            *reinterpret_cast<short8*>((char*)buf + off) = s;
        }
    }
};

// ---------------------------------------------------------------------------
// MFMA GEMM.  out[i][o] = sum_k X[i][k]*W[o][k]  (+ epilogue)
//   MODE 0: proj partial -> Yp slab (fp32); grid.y = k-split slab
//   MODE 1: + bias + agg(rows<1024) + row-L2-normalize -> bf16 out
//   MODE 2: MODE1 + relu -> fp32 out
// ---------------------------------------------------------------------------
template<int DOUT, int BM, int WM, int WN, int MODE, bool AFP32, int MINW>
__global__ __launch_bounds__(256, MINW)
void mfma_gemm(const void* __restrict__ Xv,
               const unsigned short* __restrict__ W,
               const float* __restrict__ bias,
               const float* __restrict__ aggp,
               float* __restrict__ outf,
               unsigned short* __restrict__ outb,
               int din, int kchunk)
{
    constexpr int BN = WN * 64;
    static_assert(BN == DOUT, "block must own full output rows");
    constexpr int FM = BM / (WM * 16);
    __shared__ unsigned short Abuf[BM * 64];
    __shared__ unsigned short Bbuf[BN * 64];
    __shared__ float ssred[WN * BM];

    const int t = threadIdx.x, wvid = t >> 6, lane = t & 63;
    const int wr_ = wvid / WN, wc = wvid % WN;
    const int i0 = blockIdx.x * BM;
    const int kb = (MODE == 0) ? blockIdx.y * kchunk : 0;
    const int nt = ((MODE == 0) ? kchunk : din) >> 6;

    f32x4 acc[FM][4];
#pragma unroll
    for (int fi = 0; fi < FM; ++fi)
#pragma unroll
        for (int fj = 0; fj < 4; ++fj) acc[fi][fj] = (f32x4){0.f, 0.f, 0.f, 0.f};

    RegsBF<BN> brg;
    RegsF32<BM> arf;
    RegsBF<BM> arb;
    if (AFP32) arf.load((const float*)Xv, din, i0, kb, t);
    else       arb.load((const unsigned short*)Xv, din, i0, kb, t);
    brg.load(W, din, 0, kb, t);

    for (int kt = 0; kt < nt; ++kt) {
        if (kt) __syncthreads();
        if (AFP32) arf.store(Abuf, t); else arb.store(Abuf, t);
        brg.store(Bbuf, t);
        __syncthreads();
        if (kt + 1 < nt) {
            int kn = kb + (kt + 1) * 64;
            if (AFP32) arf.load((const float*)Xv, din, i0, kn, t);
            else       arb.load((const unsigned short*)Xv, din, i0, kn, t);
            brg.load(W, din, 0, kn, t);
        }
#pragma unroll
        for (int kk = 0; kk < 2; ++kk) {
            short8 a[FM], b[4];
#pragma unroll
            for (int fi = 0; fi < FM; ++fi) {
                int rA = wr_ * (BM / WM) + fi * 16 + (lane & 15);
                int off = (rA * 128 + kk * 64 + (lane >> 4) * 16) ^ ((rA & 7) << 4);
                a[fi] = *reinterpret_cast<const short8*>((const char*)Abuf + off);
            }
#pragma unroll
            for (int fj = 0; fj < 4; ++fj) {
                int rB = wc * 64 + fj * 16 + (lane & 15);
                int off = (rB * 128 + kk * 64 + (lane >> 4) * 16) ^ ((rB & 7) << 4);
                b[fj] = *reinterpret_cast<const short8*>((const char*)Bbuf + off);
            }
#pragma unroll
            for (int fi = 0; fi < FM; ++fi)
#pragma unroll
                for (int fj = 0; fj < 4; ++fj)
                    acc[fi][fj] = __builtin_amdgcn_mfma_f32_16x16x32_bf16(
                        a[fi], b[fj], acc[fi][fj], 0, 0, 0);
        }
    }

    // C/D frag layout (m89): col = lane&15, row = (lane>>4)*4 + reg
    if (MODE == 0) {
        float* dst = outf + (size_t)blockIdx.y * KROWS * DOUT;
#pragma unroll
        for (int fi = 0; fi < FM; ++fi)
#pragma unroll
            for (int fj = 0; fj < 4; ++fj)
#pragma unroll
                for (int reg = 0; reg < 4; ++reg) {
                    int rl = wr_ * (BM / WM) + fi * 16 + ((lane >> 4) << 2) + reg;
                    int cl = wc * 64 + fj * 16 + (lane & 15);
                    dst[(size_t)(i0 + rl) * DOUT + cl] = acc[fi][fj][reg];
                }
        return;
    }

    const bool hasagg = (i0 < KROWS);
    float bb[4];
#pragma unroll
    for (int fj = 0; fj < 4; ++fj) bb[fj] = bias[wc * 64 + fj * 16 + (lane & 15)];

#pragma unroll
    for (int fi = 0; fi < FM; ++fi)
#pragma unroll
        for (int fj = 0; fj < 4; ++fj)
#pragma unroll
            for (int reg = 0; reg < 4; ++reg) {
                int rl = wr_ * (BM / WM) + fi * 16 + ((lane >> 4) << 2) + reg;
                int cl = wc * 64 + fj * 16 + (lane & 15);
                float v = acc[fi][fj][reg] + bb[fj];
                if (hasagg) v += aggp[(size_t)(i0 + rl) * DOUT + cl];
                acc[fi][fj][reg] = v;
            }

    float sstot[FM][4];
#pragma unroll
    for (int fi = 0; fi < FM; ++fi)
#pragma unroll
        for (int reg = 0; reg < 4; ++reg) {
            float s = 0.f;
#pragma unroll
            for (int fj = 0; fj < 4; ++fj) {
                float v = acc[fi][fj][reg];
                s += v * v;
            }
#pragma unroll
            for (int m = 8; m >= 1; m >>= 1) s += __shfl_xor(s, m);
            if ((lane & 15) == 0) {
                int rl = wr_ * (BM / WM) + fi * 16 + ((lane >> 4) << 2) + reg;
                ssred[wc * BM + rl] = s;
            }
        }
    __syncthreads();
#pragma unroll
    for (int fi = 0; fi < FM; ++fi)
#pragma unroll
        for (int reg = 0; reg < 4; ++reg) {
            int rl = wr_ * (BM / WM) + fi * 16 + ((lane >> 4) << 2) + reg;
            float s = 0.f;
#pragma unroll
            for (int c = 0; c < WN; ++c) s += ssred[c * BM + rl];
            sstot[fi][reg] = 1.0f / fmaxf(sqrtf(s), 1e-12f);
        }

#pragma unroll
    for (int fi = 0; fi < FM; ++fi)
#pragma unroll
        for (int fj = 0; fj < 4; ++fj)
#pragma unroll
            for (int reg = 0; reg < 4; ++reg) {
                int rl = wr_ * (BM / WM) + fi * 16 + ((lane >> 4) << 2) + reg;
                int cl = wc * 64 + fj * 16 + (lane & 15);
                float v = acc[fi][fj][reg] * sstot[fi][reg];
                if (MODE == 2) {
                    v = fmaxf(v, 0.f);
                    outf[(size_t)(i0 + rl) * DOUT + cl] = v;
                } else {
                    outb[(size_t)(i0 + rl) * DOUT + cl] = f2bf(v);
                }
            }
}

// ---- exclusive prefix-mean over 1024 rows per column -----------------------
template<int DOUT>
__global__ __launch_bounds__(256)
void scan_kernel(const float* __restrict__ Ypart, float* __restrict__ aggp,
                 int nsplit)
{
    const int o = blockIdx.x;
    const int t = threadIdx.x;
    float v[4];
#pragma unroll
    for (int j = 0; j < 4; ++j) {
        const int i = t * 4 + j;
        float s = 0.f;
        for (int sp = 0; sp < nsplit; ++sp)
            s += Ypart[(size_t)sp * KROWS * DOUT + (size_t)i * DOUT + o];
        v[j] = s;
    }
    float tot = v[0] + v[1] + v[2] + v[3];
    const int lane = t & 63;
    const int wid  = t >> 6;
    float x = tot;
#pragma unroll
    for (int d = 1; d < 64; d <<= 1) {
        float y = __shfl_up(x, d, 64);
        if (lane >= d) x += y;
    }
    __shared__ float wsum[4];
    if (lane == 63) wsum[wid] = x;
    __syncthreads();
    float base = 0.f;
    for (int ww = 0; ww < wid; ++ww) base += wsum[ww];
    float run = base + x - tot;
#pragma unroll
    for (int j = 0; j < 4; ++j) {
        const int i = t * 4 + j;
        aggp[(size_t)i * DOUT + o] = run / fmaxf((float)i, 1.0f);
        run += v[j];
    }
}

extern "C" void kernel_launch(void* const* d_in, const int* in_sizes, int n_in,
                              void* d_out, int out_size, void* d_ws, size_t ws_size,
                              hipStream_t stream)
{
    const float* flow = (const float*)d_in[0];
    const float* wl1 = (const float*)d_in[1];
    const float* bl1 = (const float*)d_in[2];
    const float* wr1 = (const float*)d_in[3];
    const float* wl2 = (const float*)d_in[4];
    const float* bl2 = (const float*)d_in[5];
    const float* wr2 = (const float*)d_in[6];
    const float* wl3 = (const float*)d_in[7];
    const float* bl3 = (const float*)d_in[8];
    const float* wr3 = (const float*)d_in[9];
    const float* wl4 = (const float*)d_in[10];
    const float* bl4 = (const float*)d_in[11];
    const float* wr4 = (const float*)d_in[12];
    float* out = (float*)d_out;

    char* p = (char*)d_ws;
    unsigned short* wbf = (unsigned short*)p;          p += 1 << 20;
    unsigned short* xA  = (unsigned short*)p;          p += (size_t)NROWS * 128 * 2;
    unsigned short* xB  = (unsigned short*)p;          p += (size_t)NROWS * 256 * 2;
    float* Yp   = (float*)p;                           p += (size_t)4 * KROWS * 256 * 4;
    float* aggp = (float*)p;

    const unsigned short* wl1b = wbf;
    const unsigned short* wr1b = wbf + 131072;
    const unsigned short* wl2b = wbf + 262144;
    const unsigned short* wr2b = wbf + 294912;
    const unsigned short* wl3b = wbf + 327680;
    const unsigned short* wr3b = wbf + 360448;
    const unsigned short* wl4b = wbf + 393216;
    const unsigned short* wr4b = wbf + 425984;

    cvt_weights<<<448, 256, 0, stream>>>(wl1, wr1, wl2, wr2, wl3, wr3, wl4, wr4,
                                         wbf, out + (size_t)NROWS * 256);

    // ---- L1: din=1024, dout=128, X = flow (fp32) ----
    mfma_gemm<128, 64, 2, 2, 0, true , 2><<<dim3(16, 4), 256, 0, stream>>>(
        flow, wl1b, nullptr, nullptr, Yp, nullptr, 1024, 256);
    scan_kernel<128><<<128, 256, 0, stream>>>(Yp, aggp, 4);
    mfma_gemm<128, 32, 2, 2, 1, true , 4><<<dim3(1024, 1), 256, 0, stream>>>(
        flow, wr1b, bl1, aggp, nullptr, xA, 1024, 1024);

    // ---- L2: din=128, dout=256 ----
    mfma_gemm<256, 64, 1, 4, 0, false, 2><<<dim3(16, 2), 256, 0, stream>>>(
        xA, wl2b, nullptr, nullptr, Yp, nullptr, 128, 64);
    scan_kernel<256><<<256, 256, 0, stream>>>(Yp, aggp, 2);
    mfma_gemm<256, 32, 1, 4, 1, false, 4><<<dim3(1024, 1), 256, 0, stream>>>(
        xA, wr2b, bl2, aggp, nullptr, xB, 128, 128);

    // ---- L3: din=256, dout=128 ----
    mfma_gemm<128, 64, 2, 2, 0, false, 2><<<dim3(16, 4), 256, 0, stream>>>(
        xB, wl3b, nullptr, nullptr, Yp, nullptr, 256, 64);
    scan_kernel<128><<<128, 256, 0, stream>>>(Yp, aggp, 4);
    mfma_gemm<128, 32, 2, 2, 1, false, 4><<<dim3(1024, 1), 256, 0, stream>>>(
        xB, wr3b, bl3, aggp, nullptr, xA, 256, 256);

    // ---- L4: din=128, dout=256, + ReLU -> fp32 out ----
    mfma_gemm<256, 64, 1, 4, 0, false, 2><<<dim3(16, 2), 256, 0, stream>>>(
        xA, wl4b, nullptr, nullptr, Yp, nullptr, 128, 64);
    scan_kernel<256><<<256, 256, 0, stream>>>(Yp, aggp, 2);
    mfma_gemm<256, 32, 1, 4, 2, false, 4><<<dim3(1024, 1), 256, 0, stream>>>(
        xA, wr4b, bl4, aggp, out, nullptr, 128, 128);
}

// Round 5
// 116.859 us; speedup vs baseline: 2.0214x; 1.1444x over previous
//
#include <hip/hip_runtime.h>
#include <math.h>

// ---------------------------------------------------------------------------
// Encoder_Flows on MI355X — 9 dispatches: cvt + 4 x (proj, main).
// Per layer: out = agg@w_l^T + b_l + x@w_r^T ; row-L2-normalize (+relu L4).
// agg affects only flattened rows [0,1024).
// agg@w_l^T = prefix_sum(Y)/cnt with Y = x[:1024]@w_l^T.
// prefix_sum(Y) = L @ Y, L = strictly-lower-triangular ones (exact in bf16):
//   proj kernel writes Y^T bf16 (DOUT x 1024); main kernel's hasagg blocks
//   run a register-generated L-fragment MFMA scan-GEMM over Y^T before the
//   bulk GEMM, keeping agg in registers. No scan dispatch, no atomics.
// All GEMMs bf16 MFMA 16x16x32, fp32 accumulate. BM=32 -> 1024 main blocks.
// XOR-swizzled LDS (T2) for conflict-free ds_read_b128.
// ---------------------------------------------------------------------------

typedef __attribute__((ext_vector_type(8))) short short8;
typedef __attribute__((ext_vector_type(4))) float f32x4;

constexpr int NROWS = 32768;
constexpr int KROWS = 1024;

static __device__ __forceinline__ unsigned short f2bf(float f) {
    unsigned int u = __float_as_uint(f);
    return (unsigned short)((u + 0x7fffu + ((u >> 16) & 1u)) >> 16);
}

// ---- weight fp32->bf16 conversion (+ tuple scalar write) ------------------
__global__ __launch_bounds__(256)
void cvt_weights(const float* __restrict__ wl1, const float* __restrict__ wr1,
                 const float* __restrict__ wl2, const float* __restrict__ wr2,
                 const float* __restrict__ wl3, const float* __restrict__ wr3,
                 const float* __restrict__ wl4, const float* __restrict__ wr4,
                 unsigned short* __restrict__ dst, float* __restrict__ outscalar)
{
    if (blockIdx.x == 0 && threadIdx.x == 0) outscalar[0] = 1.0f;
    int g = (blockIdx.x * 256 + threadIdx.x) * 4;
    const float* src; int off;
    if      (g < 131072) { src = wl1; off = g; }
    else if (g < 262144) { src = wr1; off = g - 131072; }
    else if (g < 294912) { src = wl2; off = g - 262144; }
    else if (g < 327680) { src = wr2; off = g - 294912; }
    else if (g < 360448) { src = wl3; off = g - 327680; }
    else if (g < 393216) { src = wr3; off = g - 360448; }
    else if (g < 425984) { src = wl4; off = g - 393216; }
    else                 { src = wr4; off = g - 425984; }
    float4 v = *reinterpret_cast<const float4*>(src + off);
    ushort4 o;
    o.x = f2bf(v.x); o.y = f2bf(v.y); o.z = f2bf(v.z); o.w = f2bf(v.w);
    *reinterpret_cast<ushort4*>(dst + g) = o;
}

// ---- register staging helpers (tile ROWS x 64, XOR-swizzled LDS) ----------
template<int ROWS>
struct RegsBF {
    short8 v[ROWS / 32];
    __device__ __forceinline__ void load(const unsigned short* src, int ld,
                                         int r0, int k0, int t) {
#pragma unroll
        for (int j = 0; j < ROWS / 32; ++j) {
            int idx = j * 256 + t; int r = idx >> 3, f = idx & 7;
            v[j] = *reinterpret_cast<const short8*>(
                src + (size_t)(r0 + r) * ld + k0 + f * 8);
        }
    }
    __device__ __forceinline__ void store(unsigned short* buf, int t) {
#pragma unroll
        for (int j = 0; j < ROWS / 32; ++j) {
            int idx = j * 256 + t; int r = idx >> 3, f = idx & 7;
            int off = (r * 128 + f * 16) ^ ((r & 7) << 4);
            *reinterpret_cast<short8*>((char*)buf + off) = v[j];
        }
    }
};

template<int ROWS>
struct RegsF32 {
    float4 v[ROWS / 16];
    __device__ __forceinline__ void load(const float* src, int ld,
                                         int r0, int k0, int t) {
#pragma unroll
        for (int j = 0; j < ROWS / 32; ++j) {
            int idx = j * 256 + t; int r = idx >> 3, f = idx & 7;
            const float* p = src + (size_t)(r0 + r) * ld + k0 + f * 8;
            v[2 * j]     = *reinterpret_cast<const float4*>(p);
            v[2 * j + 1] = *reinterpret_cast<const float4*>(p + 4);
        }
    }
    __device__ __forceinline__ void store(unsigned short* buf, int t) {
#pragma unroll
        for (int j = 0; j < ROWS / 32; ++j) {
            int idx = j * 256 + t; int r = idx >> 3, f = idx & 7;
            float4 a = v[2 * j], b = v[2 * j + 1];
            short8 s;
            s[0] = (short)f2bf(a.x); s[1] = (short)f2bf(a.y);
            s[2] = (short)f2bf(a.z); s[3] = (short)f2bf(a.w);
            s[4] = (short)f2bf(b.x); s[5] = (short)f2bf(b.y);
            s[6] = (short)f2bf(b.z); s[7] = (short)f2bf(b.w);
            int off = (r * 128 + f * 16) ^ ((r & 7) << 4);
            *reinterpret_cast<short8*>((char*)buf + off) = s;
        }
    }
};

// ---------------------------------------------------------------------------
// MFMA GEMM.  out[i][o] = sum_k X[i][k]*W[o][k]  (+ epilogue)
//   MODE 0: proj -> write Y^T bf16 (DOUT x 1024) to outb
//   MODE 1: scan-GEMM(agg) + bias + agg + row-L2-normalize -> bf16 out
//   MODE 2: MODE1 + relu -> fp32 out
// ---------------------------------------------------------------------------
template<int DOUT, int BM, int WM, int WN, int MODE, bool AFP32, int MINW>
__global__ __launch_bounds__(256, MINW)
void mfma_gemm(const void* __restrict__ Xv,
               const unsigned short* __restrict__ W,
               const float* __restrict__ bias,
               const unsigned short* __restrict__ YT,  // (DOUT, 1024) bf16
               float* __restrict__ outf,
               unsigned short* __restrict__ outb,
               int din)
{
    constexpr int BN = WN * 64;
    static_assert(BN == DOUT, "block must own full output rows");
    constexpr int FM = BM / (WM * 16);
    __shared__ unsigned short Abuf[BM * 64];
    __shared__ unsigned short Bbuf[BN * 64];
    __shared__ float ssred[WN * BM];

    const int t = threadIdx.x, wvid = t >> 6, lane = t & 63;
    const int wr_ = wvid / WN, wc = wvid % WN;
    const int i0 = blockIdx.x * BM;
    const int nt = din >> 6;
    const bool hasagg = (MODE != 0) && (i0 < KROWS);

    // ---- agg via scan-GEMM: agg_rows = L[i0..i0+BM) @ Y, from Y^T bf16 ----
    f32x4 agg[FM][4];
#pragma unroll
    for (int fi = 0; fi < FM; ++fi)
#pragma unroll
        for (int fj = 0; fj < 4; ++fj) agg[fi][fj] = (f32x4){0.f, 0.f, 0.f, 0.f};

    if (hasagg) {
        const int nt2 = (i0 + BM + 63) >> 6;    // rows only need j < i
        RegsBF<BN> sb;
        sb.load(YT, KROWS, 0, 0, t);
        for (int kt = 0; kt < nt2; ++kt) {
            if (kt) __syncthreads();
            sb.store(Bbuf, t);
            __syncthreads();
            if (kt + 1 < nt2) sb.load(YT, KROWS, 0, (kt + 1) * 64, t);
#pragma unroll
            for (int kk = 0; kk < 2; ++kk) {
                short8 a[FM], b[4];
                const int jb = kt * 64 + kk * 32 + ((lane >> 4) << 3);
#pragma unroll
                for (int fi = 0; fi < FM; ++fi) {
                    const int irow = i0 + wr_ * (BM / WM) + fi * 16 + (lane & 15);
#pragma unroll
                    for (int e = 0; e < 8; ++e)
                        a[fi][e] = (short)((jb + e < irow) ? 0x3F80 : 0);
                }
#pragma unroll
                for (int fj = 0; fj < 4; ++fj) {
                    int rB = wc * 64 + fj * 16 + (lane & 15);
                    int off = (rB * 128 + kk * 64 + (lane >> 4) * 16) ^ ((rB & 7) << 4);
                    b[fj] = *reinterpret_cast<const short8*>((const char*)Bbuf + off);
                }
#pragma unroll
                for (int fi = 0; fi < FM; ++fi)
#pragma unroll
                    for (int fj = 0; fj < 4; ++fj)
                        agg[fi][fj] = __builtin_amdgcn_mfma_f32_16x16x32_bf16(
                            a[fi], b[fj], agg[fi][fj], 0, 0, 0);
            }
        }
        // divide by cnt = max(row, 1); C/D row = (lane>>4)*4 + reg
#pragma unroll
        for (int fi = 0; fi < FM; ++fi)
#pragma unroll
            for (int reg = 0; reg < 4; ++reg) {
                int i_abs = i0 + wr_ * (BM / WM) + fi * 16 + ((lane >> 4) << 2) + reg;
                float inv = 1.0f / (float)(i_abs > 1 ? i_abs : 1);
#pragma unroll
                for (int fj = 0; fj < 4; ++fj) agg[fi][fj][reg] *= inv;
            }
        __syncthreads();                        // Bbuf reads done before reuse
    }

    // ---- bulk GEMM ----
    f32x4 acc[FM][4];
#pragma unroll
    for (int fi = 0; fi < FM; ++fi)
#pragma unroll
        for (int fj = 0; fj < 4; ++fj) acc[fi][fj] = (f32x4){0.f, 0.f, 0.f, 0.f};

    RegsBF<BN> brg;
    RegsF32<BM> arf;
    RegsBF<BM> arb;
    if (AFP32) arf.load((const float*)Xv, din, i0, 0, t);
    else       arb.load((const unsigned short*)Xv, din, i0, 0, t);
    brg.load(W, din, 0, 0, t);

    for (int kt = 0; kt < nt; ++kt) {
        if (kt) __syncthreads();
        if (AFP32) arf.store(Abuf, t); else arb.store(Abuf, t);
        brg.store(Bbuf, t);
        __syncthreads();
        if (kt + 1 < nt) {
            int kn = (kt + 1) * 64;
            if (AFP32) arf.load((const float*)Xv, din, i0, kn, t);
            else       arb.load((const unsigned short*)Xv, din, i0, kn, t);
            brg.load(W, din, 0, kn, t);
        }
#pragma unroll
        for (int kk = 0; kk < 2; ++kk) {
            short8 a[FM], b[4];
#pragma unroll
            for (int fi = 0; fi < FM; ++fi) {
                int rA = wr_ * (BM / WM) + fi * 16 + (lane & 15);
                int off = (rA * 128 + kk * 64 + (lane >> 4) * 16) ^ ((rA & 7) << 4);
                a[fi] = *reinterpret_cast<const short8*>((const char*)Abuf + off);
            }
#pragma unroll
            for (int fj = 0; fj < 4; ++fj) {
                int rB = wc * 64 + fj * 16 + (lane & 15);
                int off = (rB * 128 + kk * 64 + (lane >> 4) * 16) ^ ((rB & 7) << 4);
                b[fj] = *reinterpret_cast<const short8*>((const char*)Bbuf + off);
            }
#pragma unroll
            for (int fi = 0; fi < FM; ++fi)
#pragma unroll
                for (int fj = 0; fj < 4; ++fj)
                    acc[fi][fj] = __builtin_amdgcn_mfma_f32_16x16x32_bf16(
                        a[fi], b[fj], acc[fi][fj], 0, 0, 0);
        }
    }

    // C/D frag layout (m89): col = lane&15, row = (lane>>4)*4 + reg
    if (MODE == 0) {
        // write Y^T bf16: YT[col][i0+row]; 4 consecutive regs -> 8B store
#pragma unroll
        for (int fi = 0; fi < FM; ++fi)
#pragma unroll
            for (int fj = 0; fj < 4; ++fj) {
                int rl0 = wr_ * (BM / WM) + fi * 16 + ((lane >> 4) << 2);
                int cl  = wc * 64 + fj * 16 + (lane & 15);
                ushort4 y;
                y.x = f2bf(acc[fi][fj][0]); y.y = f2bf(acc[fi][fj][1]);
                y.z = f2bf(acc[fi][fj][2]); y.w = f2bf(acc[fi][fj][3]);
                *reinterpret_cast<ushort4*>(
                    outb + (size_t)cl * KROWS + i0 + rl0) = y;
            }
        return;
    }

    float bb[4];
#pragma unroll
    for (int fj = 0; fj < 4; ++fj) bb[fj] = bias[wc * 64 + fj * 16 + (lane & 15)];

#pragma unroll
    for (int fi = 0; fi < FM; ++fi)
#pragma unroll
        for (int fj = 0; fj < 4; ++fj)
#pragma unroll
            for (int reg = 0; reg < 4; ++reg)
                acc[fi][fj][reg] += bb[fj] + agg[fi][fj][reg];

    float sstot[FM][4];
#pragma unroll
    for (int fi = 0; fi < FM; ++fi)
#pragma unroll
        for (int reg = 0; reg < 4; ++reg) {
            float s = 0.f;
#pragma unroll
            for (int fj = 0; fj < 4; ++fj) {
                float v = acc[fi][fj][reg];
                s += v * v;
            }
#pragma unroll
            for (int m = 8; m >= 1; m >>= 1) s += __shfl_xor(s, m);
            if ((lane & 15) == 0) {
                int rl = wr_ * (BM / WM) + fi * 16 + ((lane >> 4) << 2) + reg;
                ssred[wc * BM + rl] = s;
            }
        }
    __syncthreads();
#pragma unroll
    for (int fi = 0; fi < FM; ++fi)
#pragma unroll
        for (int reg = 0; reg < 4; ++reg) {
            int rl = wr_ * (BM / WM) + fi * 16 + ((lane >> 4) << 2) + reg;
            float s = 0.f;
#pragma unroll
            for (int c = 0; c < WN; ++c) s += ssred[c * BM + rl];
            sstot[fi][reg] = 1.0f / fmaxf(sqrtf(s), 1e-12f);
        }

#pragma unroll
    for (int fi = 0; fi < FM; ++fi)
#pragma unroll
        for (int fj = 0; fj < 4; ++fj)
#pragma unroll
            for (int reg = 0; reg < 4; ++reg) {
                int rl = wr_ * (BM / WM) + fi * 16 + ((lane >> 4) << 2) + reg;
                int cl = wc * 64 + fj * 16 + (lane & 15);
                float v = acc[fi][fj][reg] * sstot[fi][reg];
                if (MODE == 2) {
                    v = fmaxf(v, 0.f);
                    outf[(size_t)(i0 + rl) * DOUT + cl] = v;
                } else {
                    outb[(size_t)(i0 + rl) * DOUT + cl] = f2bf(v);
                }
            }
}

extern "C" void kernel_launch(void* const* d_in, const int* in_sizes, int n_in,
                              void* d_out, int out_size, void* d_ws, size_t ws_size,
                              hipStream_t stream)
{
    const float* flow = (const float*)d_in[0];
    const float* wl1 = (const float*)d_in[1];
    const float* bl1 = (const float*)d_in[2];
    const float* wr1 = (const float*)d_in[3];
    const float* wl2 = (const float*)d_in[4];
    const float* bl2 = (const float*)d_in[5];
    const float* wr2 = (const float*)d_in[6];
    const float* wl3 = (const float*)d_in[7];
    const float* bl3 = (const float*)d_in[8];
    const float* wr3 = (const float*)d_in[9];
    const float* wl4 = (const float*)d_in[10];
    const float* bl4 = (const float*)d_in[11];
    const float* wr4 = (const float*)d_in[12];
    float* out = (float*)d_out;

    char* p = (char*)d_ws;
    unsigned short* wbf = (unsigned short*)p;  p += 1 << 20;
    unsigned short* xA  = (unsigned short*)p;  p += (size_t)NROWS * 128 * 2;
    unsigned short* xB  = (unsigned short*)p;  p += (size_t)NROWS * 256 * 2;
    unsigned short* YT1 = (unsigned short*)p;  p += (size_t)128 * KROWS * 2;
    unsigned short* YT2 = (unsigned short*)p;  p += (size_t)256 * KROWS * 2;
    unsigned short* YT3 = (unsigned short*)p;  p += (size_t)128 * KROWS * 2;
    unsigned short* YT4 = (unsigned short*)p;

    const unsigned short* wl1b = wbf;
    const unsigned short* wr1b = wbf + 131072;
    const unsigned short* wl2b = wbf + 262144;
    const unsigned short* wr2b = wbf + 294912;
    const unsigned short* wl3b = wbf + 327680;
    const unsigned short* wr3b = wbf + 360448;
    const unsigned short* wl4b = wbf + 393216;
    const unsigned short* wr4b = wbf + 425984;

    cvt_weights<<<448, 256, 0, stream>>>(wl1, wr1, wl2, wr2, wl3, wr3, wl4, wr4,
                                         wbf, out + (size_t)NROWS * 256);

    // ---- L1: din=1024, dout=128, X = flow (fp32) ----
    mfma_gemm<128, 32, 2, 2, 0, true , 2><<<32, 256, 0, stream>>>(
        flow, wl1b, nullptr, nullptr, nullptr, YT1, 1024);
    mfma_gemm<128, 32, 2, 2, 1, true , 4><<<1024, 256, 0, stream>>>(
        flow, wr1b, bl1, YT1, nullptr, xA, 1024);

    // ---- L2: din=128, dout=256 ----
    mfma_gemm<256, 32, 1, 4, 0, false, 2><<<32, 256, 0, stream>>>(
        xA, wl2b, nullptr, nullptr, nullptr, YT2, 128);
    mfma_gemm<256, 32, 1, 4, 1, false, 3><<<1024, 256, 0, stream>>>(
        xA, wr2b, bl2, YT2, nullptr, xB, 128);

    // ---- L3: din=256, dout=128 ----
    mfma_gemm<128, 32, 2, 2, 0, false, 2><<<32, 256, 0, stream>>>(
        xB, wl3b, nullptr, nullptr, nullptr, YT3, 256);
    mfma_gemm<128, 32, 2, 2, 1, false, 4><<<1024, 256, 0, stream>>>(
        xB, wr3b, bl3, YT3, nullptr, xA, 256);

    // ---- L4: din=128, dout=256, + ReLU -> fp32 out ----
    mfma_gemm<256, 32, 1, 4, 0, false, 2><<<32, 256, 0, stream>>>(
        xA, wl4b, nullptr, nullptr, nullptr, YT4, 128);
    mfma_gemm<256, 32, 1, 4, 2, false, 3><<<1024, 256, 0, stream>>>(
        xA, wr4b, bl4, YT4, out, nullptr, 128);
}